// Round 6
// baseline (2405.096 us; speedup 1.0000x reference)
//
#include <hip/hip_runtime.h>
#include <hip/hip_bf16.h>
#include <stdint.h>

#define TT 1024
#define BB 512
#define II 128
#define HH 256
#define NKC 12          // K = 384 = 12 chunks of 32 (x:0..127, h:128..383)
#define GSTR 132        // gates LDS row stride (floats): 2-way bank alias = free

typedef __attribute__((ext_vector_type(8))) short bf16x8;
typedef __attribute__((ext_vector_type(4))) float f32x4;
typedef __attribute__((ext_vector_type(4))) uint32_t u32x4;
typedef unsigned long long ull;

__device__ __forceinline__ float fsig(float x)  { return 1.0f / (1.0f + __expf(-x)); }
__device__ __forceinline__ float ftanh(float x) { return 1.0f - 2.0f / (__expf(2.0f * x) + 1.0f); }
__device__ __forceinline__ uint16_t f2bf(float f) {
    return __bfloat16_as_ushort(__float2bfloat16(f));
}
__device__ __forceinline__ float bf2lo(uint32_t w) { return __uint_as_float(w << 16); }
__device__ __forceinline__ float bf2hi(uint32_t w) { return __uint_as_float(w & 0xffff0000u); }

// ============================================================================
// 256 blocks = 32 groups x 8 roles; the bid remap puts a group's 8 roles on one
// XCD under round-robin dispatch (perf heuristic only). Exchange words are
// {stamp32 | 2xbf16}; published to BOTH a fast copy (sc0 -> shared L2, valid
// only if the peer shares this XCD's L2) and a slow copy (sc0 sc1 -> IF,
// always coherent). Consumer polls both; uses whichever is fresh. Placement-
// independent correctness, L2-latency exchange when placement cooperates.
// ============================================================================
template<int DUAL>
__global__ __launch_bounds__(512, 1) void lstm_kernel(
    const float* __restrict__ x,
    const float* __restrict__ h0, const float* __restrict__ c0,
    const float* __restrict__ z0,
    const float* __restrict__ W_ih, const float* __restrict__ W_hh,
    const float* __restrict__ b_ih, const float* __restrict__ b_hh,
    const float* __restrict__ Wfc, const float* __restrict__ bfc,
    ull* __restrict__ hbF, ull* __restrict__ hbS,
    float* __restrict__ out)
{
    __shared__ __align__(16) uint16_t w_sh[NKC * 8 * 64 * 8];  // 96 KB weights
    __shared__ __align__(16) uint16_t a_sh[NKC * 4 * 16 * 8];  // 12 KB A-frags
    __shared__ float g_sh[16 * GSTR];
    __shared__ float zp_sh[2][8][16];

    const int tid  = threadIdx.x;
    const int lane = tid & 63, wv = tid >> 6;
    // same-XCD remap: bid&7 (the XCD under round-robin) identical per group
    const int bid  = blockIdx.x;
    const int mm   = bid >> 3;
    const int role = mm & 7, grp = (bid & 7) * 4 + (mm >> 3);
    const int b0   = grp * 16;
    const int arow = tid >> 5, auu = tid & 31;     // activation: 1 cell/thread
    const int u_g  = role * 32 + auu;
    const int xc   = (tid & 31) * 4;               // x-stage role
    const int grole = wv, grow = (tid >> 2) & 15, gwq = tid & 3;  // gather role

    // ---- one-time: swizzle this block's weight slice straight into LDS ----
    #pragma unroll
    for (int i = 0; i < 12; ++i) {
        int eo = i * 512 + tid;
        int lane2 = eo & 63, knt = eo >> 6;
        int nt = knt & 7;
        int k0 = (knt >> 3) * 32 + (lane2 >> 4) * 8;
        int lc = nt * 16 + (lane2 & 15);
        int col = (lc >> 5) * 256 + role * 32 + (lc & 31);
        const float* src = (k0 < II) ? &W_ih[(size_t)col * (II + 1) + k0]
                                     : &W_hh[(size_t)col * HH + (k0 - II)];
        ushort4 lo, hi;
        lo.x = f2bf(src[0]); lo.y = f2bf(src[1]); lo.z = f2bf(src[2]); lo.w = f2bf(src[3]);
        hi.x = f2bf(src[4]); hi.y = f2bf(src[5]); hi.z = f2bf(src[6]); hi.w = f2bf(src[7]);
        *(ushort4*)&w_sh[eo * 8 + 0] = lo;
        *(ushort4*)&w_sh[eo * 8 + 4] = hi;
    }

    // ---- per-thread loop invariants ----
    float bia[4], wzv[4];
    #pragma unroll
    for (int g = 0; g < 4; ++g) {
        int c = g * 256 + u_g;
        bia[g] = b_ih[c] + b_hh[c];
        wzv[g] = W_ih[(size_t)c * (II + 1) + II];   // z column (col 128)
    }
    float wfc8[8];
    #pragma unroll
    for (int j = 0; j < 8; ++j) wfc8[j] = Wfc[grole * 32 + gwq * 8 + j];
    const float bfcs = bfc[0];
    const float z0r  = z0[b0 + arow];
    float c_r = c0[(size_t)(b0 + arow) * HH + u_g];

    // ---- h0 -> a_sh (all roles), x0 -> a_sh ----
    {
        const float* hp = h0 + (size_t)(b0 + grow) * HH + grole * 32 + gwq * 8;
        uint4 pw;
        pw.x = (uint32_t)f2bf(hp[0]) | ((uint32_t)f2bf(hp[1]) << 16);
        pw.y = (uint32_t)f2bf(hp[2]) | ((uint32_t)f2bf(hp[3]) << 16);
        pw.z = (uint32_t)f2bf(hp[4]) | ((uint32_t)f2bf(hp[5]) << 16);
        pw.w = (uint32_t)f2bf(hp[6]) | ((uint32_t)f2bf(hp[7]) << 16);
        *(uint4*)&a_sh[(((4 + grole) * 4 + gwq) * 16 + grow) * 8] = pw;
    }
    {
        float4 xv = *(const float4*)&x[(size_t)(b0 + arow) * II + xc];
        int kcx = xc >> 5, gx = (xc >> 3) & 3, jx = xc & 7;
        ushort4 p;
        p.x = f2bf(xv.x); p.y = f2bf(xv.y); p.z = f2bf(xv.z); p.w = f2bf(xv.w);
        *(ushort4*)&a_sh[((kcx * 4 + gx) * 16 + arow) * 8 + jx] = p;
    }

    for (int t = 0; t <= TT; ++t) {
        // prefetch x_{t+1} (issued before the poll; consumed after barrier B)
        float4 xn = make_float4(0.f, 0.f, 0.f, 0.f);
        if (t + 1 < TT)
            xn = *(const float4*)&x[(size_t)(t + 1) * (BB * II) + (size_t)(b0 + arow) * II + xc];

        if (t > 0) {
            const int par = (t - 1) & 1;
            const size_t gidx = ((((size_t)par * 32 + grp) * 8 + grole) * 16 + grow) * 16
                              + gwq * 4;
            const ull* pF = hbF + gidx;
            const ull* pS = hbS + gidx;
            u32x4 a0, a1;
            uint32_t it = 0;
            const uint32_t tt = (uint32_t)t;
            for (;;) {
                u32x4 s0, s1;
                if (DUAL) {
                    u32x4 f0, f1;
                    asm volatile(
                        "global_load_dwordx4 %0, %4, off sc0\n\t"
                        "global_load_dwordx4 %1, %4, off offset:16 sc0\n\t"
                        "global_load_dwordx4 %2, %5, off sc0 sc1\n\t"
                        "global_load_dwordx4 %3, %5, off offset:16 sc0 sc1\n\t"
                        "s_waitcnt vmcnt(0)"
                        : "=v"(f0), "=v"(f1), "=v"(s0), "=v"(s1)
                        : "v"(pF), "v"(pS) : "memory");
                    uint32_t mF = min(min(f0.y, f0.w), min(f1.y, f1.w));
                    if (mF >= tt) { a0 = f0; a1 = f1; break; }
                } else {
                    asm volatile(
                        "global_load_dwordx4 %0, %2, off sc0 sc1\n\t"
                        "global_load_dwordx4 %1, %2, off offset:16 sc0 sc1\n\t"
                        "s_waitcnt vmcnt(0)"
                        : "=v"(s0), "=v"(s1)
                        : "v"(pS) : "memory");
                }
                uint32_t mS = min(min(s0.y, s0.w), min(s1.y, s1.w));
                if (mS >= tt) { a0 = s0; a1 = s1; break; }
                __builtin_amdgcn_s_sleep(1);
                if (++it > (1u << 22)) { a0 = s0; a1 = s1; break; }  // hang-safety
            }
            uint32_t w0 = a0.x, w1 = a0.z, w2 = a1.x, w3 = a1.z;
            uint4 pw; pw.x = w0; pw.y = w1; pw.z = w2; pw.w = w3;
            *(uint4*)&a_sh[(((4 + grole) * 4 + gwq) * 16 + grow) * 8] = pw;
            float p = bf2lo(w0) * wfc8[0] + bf2hi(w0) * wfc8[1]
                    + bf2lo(w1) * wfc8[2] + bf2hi(w1) * wfc8[3]
                    + bf2lo(w2) * wfc8[4] + bf2hi(w2) * wfc8[5]
                    + bf2lo(w3) * wfc8[6] + bf2hi(w3) * wfc8[7];
            p += __shfl_xor(p, 1, 64);
            p += __shfl_xor(p, 2, 64);
            if (gwq == 0) zp_sh[t & 1][grole][grow] = p;
        }
        __syncthreads();  // A: a_sh (x_t, h_{t-1}) + zp_sh ready

        if (t == TT) {    // epilogue: emit z_{TT-1} only
            if (role == 0 && tid < 16) {
                float s = bfcs;
                #pragma unroll
                for (int r = 0; r < 8; ++r) s += zp_sh[TT & 1][r][tid];
                out[(size_t)(TT - 1) * BB + b0 + tid] = ftanh(s);
            }
            break;
        }

        // ---- MFMA: gates[16][128] = A[16][384] * Wslice, wave = n-tile ----
        f32x4 acc0 = {0.f, 0.f, 0.f, 0.f}, acc1 = {0.f, 0.f, 0.f, 0.f};
        #pragma unroll
        for (int kc = 0; kc < NKC; kc += 2) {
            bf16x8 a0 = *(const bf16x8*)&a_sh[((kc * 4 + (lane >> 4)) * 16 + (lane & 15)) * 8];
            bf16x8 bv0 = *(const bf16x8*)&w_sh[((kc * 8 + wv) * 64 + lane) * 8];
            acc0 = __builtin_amdgcn_mfma_f32_16x16x32_bf16(a0, bv0, acc0, 0, 0, 0);
            bf16x8 a1 = *(const bf16x8*)&a_sh[(((kc + 1) * 4 + (lane >> 4)) * 16 + (lane & 15)) * 8];
            bf16x8 bv1 = *(const bf16x8*)&w_sh[(((kc + 1) * 8 + wv) * 64 + lane) * 8];
            acc1 = __builtin_amdgcn_mfma_f32_16x16x32_bf16(a1, bv1, acc1, 0, 0, 0);
        }
        f32x4 acc = acc0 + acc1;
        {
            int r0 = (lane >> 4) * 4, cb = wv * 16 + (lane & 15);
            #pragma unroll
            for (int i = 0; i < 4; ++i) g_sh[(r0 + i) * GSTR + cb] = acc[i];
        }
        __syncthreads();  // B: gates ready; all a_sh reads done

        // stage x_{t+1}
        {
            int kcx = xc >> 5, gx = (xc >> 3) & 3, jx = xc & 7;
            ushort4 p;
            p.x = f2bf(xn.x); p.y = f2bf(xn.y); p.z = f2bf(xn.z); p.w = f2bf(xn.w);
            *(ushort4*)&a_sh[((kcx * 4 + gx) * 16 + arow) * 8 + jx] = p;
        }

        // ---- activation: one cell per thread ----
        float zp_;
        if (t == 0) {
            zp_ = z0r;
        } else {
            float s = bfcs;
            #pragma unroll
            for (int r = 0; r < 8; ++r) s += zp_sh[t & 1][r][arow];
            zp_ = ftanh(s);
            if (role == 0 && auu == 0)
                out[(size_t)(t - 1) * BB + b0 + arow] = zp_;
        }
        float gi = g_sh[arow * GSTR +      auu] + bia[0] + wzv[0] * zp_;
        float gf = g_sh[arow * GSTR + 32 + auu] + bia[1] + wzv[1] * zp_;
        float gg = g_sh[arow * GSTR + 64 + auu] + bia[2] + wzv[2] * zp_;
        float go = g_sh[arow * GSTR + 96 + auu] + bia[3] + wzv[3] * zp_;
        float ig = fsig(gi), fg = fsig(gf), gc = ftanh(gg), og = fsig(go);
        float cn = fg * c_r + ig * gc;
        c_r = cn;
        float hn = og * ftanh(cn);

        // publish {stamp t+1 | h pair} to fast (L2) and slow (IF) copies
        uint32_t hb16 = f2bf(hn);
        uint32_t nb = __shfl_down(hb16, 1, 64);
        if (!(auu & 1)) {
            ull q = ((ull)(uint32_t)(t + 1) << 32) | (ull)(hb16 | (nb << 16));
            size_t o = ((((size_t)(t & 1) * 32 + grp) * 8 + role) * 16 + arow) * 16
                     + (auu >> 1);
            if (DUAL)
                asm volatile("global_store_dwordx2 %0, %1, off sc0"
                             :: "v"(hbF + o), "v"(q) : "memory");
            asm volatile("global_store_dwordx2 %0, %1, off sc0 sc1"
                         :: "v"(hbS + o), "v"(q) : "memory");
        }

        if (t == TT - 1) {
            size_t ho = (size_t)TT * BB + (size_t)(b0 + arow) * HH + u_g;
            out[ho] = hn;
            out[ho + (size_t)BB * HH] = cn;
        }
        // no barrier C: stamps make publishes self-synchronizing
    }
}

extern "C" void kernel_launch(void* const* d_in, const int* in_sizes, int n_in,
                              void* d_out, int out_size, void* d_ws, size_t ws_size,
                              hipStream_t stream) {
    const float* x    = (const float*)d_in[0];
    const float* h0   = (const float*)d_in[1];
    const float* c0   = (const float*)d_in[2];
    const float* z0   = (const float*)d_in[3];
    const float* W_ih = (const float*)d_in[4];
    const float* W_hh = (const float*)d_in[5];
    const float* b_ih = (const float*)d_in[6];
    const float* b_hh = (const float*)d_in[7];
    const float* Wfc  = (const float*)d_in[8];
    const float* bfc  = (const float*)d_in[9];
    float* out = (float*)d_out;

    const size_t COPY = (size_t)2 * 32 * 8 * 16 * 16 * 8;  // 1 MB per copy
    if (ws_size >= 2 * COPY) {
        ull* hbF = (ull*)d_ws;
        ull* hbS = (ull*)((char*)d_ws + COPY);
        hipMemsetAsync(d_ws, 0, 2 * COPY, stream);  // zero stamps (replay-safe)
        lstm_kernel<1><<<256, 512, 0, stream>>>(x, h0, c0, z0, W_ih, W_hh,
                                                b_ih, b_hh, Wfc, bfc,
                                                hbF, hbS, out);
    } else {
        ull* hbS = (ull*)d_ws;
        hipMemsetAsync(d_ws, 0, COPY, stream);
        lstm_kernel<0><<<256, 512, 0, stream>>>(x, h0, c0, z0, W_ih, W_hh,
                                                b_ih, b_hh, Wfc, bfc,
                                                hbS, hbS, out);
    }
}

// Round 7
// 2185.402 us; speedup vs baseline: 1.1005x; 1.1005x over previous
//
#include <hip/hip_runtime.h>
#include <hip/hip_bf16.h>
#include <stdint.h>

#define TT 1024
#define BB 512
#define II 128
#define HH 256
#define NKC 12          // K = 384 = 12 chunks of 32 (x:0..127, h:128..383)
#define GSTR 132        // gates LDS row stride (floats): 2-way bank alias = free

typedef __attribute__((ext_vector_type(8))) short bf16x8;
typedef __attribute__((ext_vector_type(4))) float f32x4;
typedef __attribute__((ext_vector_type(4))) uint32_t u32x4;
typedef unsigned long long ull;

__device__ __forceinline__ float fsig(float x)  { return 1.0f / (1.0f + __expf(-x)); }
__device__ __forceinline__ float ftanh(float x) { return 1.0f - 2.0f / (__expf(2.0f * x) + 1.0f); }
__device__ __forceinline__ uint16_t f2bf(float f) {
    return __bfloat16_as_ushort(__float2bfloat16(f));
}
__device__ __forceinline__ float bf2lo(uint32_t w) { return __uint_as_float(w << 16); }
__device__ __forceinline__ float bf2hi(uint32_t w) { return __uint_as_float(w & 0xffff0000u); }

// ============================================================================
// 256 blocks = 32 groups x 8 roles; bid remap puts a group's 8 roles on one XCD
// under round-robin dispatch (perf heuristic only). Exchange words: 8B
// {stamp32 | 2xbf16}, published to a fast copy (sc0 -> producer L2; valid for
// same-XCD peers) and a slow copy (sc0 sc1 -> IF; always coherent). Consumer
// polls fast-only each iteration (own waitcnt!), slow every 8th as fallback.
// Weights live in VGPRs (48/thread); own-role h short-circuits through LDS.
// ============================================================================
template<int DUAL>
__global__ __launch_bounds__(512, 1) void lstm_kernel(
    const float* __restrict__ x,
    const float* __restrict__ h0, const float* __restrict__ c0,
    const float* __restrict__ z0,
    const float* __restrict__ W_ih, const float* __restrict__ W_hh,
    const float* __restrict__ b_ih, const float* __restrict__ b_hh,
    const float* __restrict__ Wfc, const float* __restrict__ bfc,
    ull* __restrict__ hbF, ull* __restrict__ hbS,
    float* __restrict__ out)
{
    __shared__ __align__(16) uint16_t a_sh[NKC * 4 * 16 * 8];  // 12 KB A-frags
    __shared__ float g_sh[16 * GSTR];                          // 8448 B gates
    __shared__ float zp_sh[2][8][16];                          // z partials

    const int tid  = threadIdx.x;
    const int lane = tid & 63, wv = tid >> 6;
    // same-XCD remap: bid&7 (the XCD under round-robin) identical per group
    const int bid  = blockIdx.x;
    const int mm   = bid >> 3;
    const int role = mm & 7, grp = (bid & 7) * 4 + (mm >> 3);
    const int b0   = grp * 16;
    const int arow = tid >> 5, auu = tid & 31;     // activation: 1 cell/thread
    const int u_g  = role * 32 + auu;
    const int xc   = (tid & 31) * 4;               // x-stage role
    const int grole = wv, grow = (tid >> 2) & 15, gwq = tid & 3;  // gather role

    // ---- one-time: this wave's weight B-fragments -> registers (48 VGPRs) ----
    bf16x8 wreg[NKC];
    {
        int lc = wv * 16 + (lane & 15);
        int col = (lc >> 5) * 256 + role * 32 + (lc & 31);
        #pragma unroll
        for (int kc = 0; kc < NKC; ++kc) {
            int k0 = kc * 32 + (lane >> 4) * 8;
            const float* src = (k0 < II) ? &W_ih[(size_t)col * (II + 1) + k0]
                                         : &W_hh[(size_t)col * HH + (k0 - II)];
            bf16x8 wv8;
            #pragma unroll
            for (int j = 0; j < 8; ++j) wv8[j] = (short)f2bf(src[j]);
            wreg[kc] = wv8;
        }
    }

    // ---- per-thread loop invariants ----
    float bia[4], wzv[4];
    #pragma unroll
    for (int g = 0; g < 4; ++g) {
        int c = g * 256 + u_g;
        bia[g] = b_ih[c] + b_hh[c];
        wzv[g] = W_ih[(size_t)c * (II + 1) + II];   // z column (col 128)
    }
    float wfc8[8];
    #pragma unroll
    for (int j = 0; j < 8; ++j) wfc8[j] = Wfc[grole * 32 + gwq * 8 + j];
    const float wfc  = Wfc[u_g];
    const float bfcs = bfc[0];
    const float z0r  = z0[b0 + arow];
    float c_r = c0[(size_t)(b0 + arow) * HH + u_g];

    // ---- h0 -> a_sh (all roles), x0 -> a_sh ----
    {
        const float* hp = h0 + (size_t)(b0 + grow) * HH + grole * 32 + gwq * 8;
        uint4 pw;
        pw.x = (uint32_t)f2bf(hp[0]) | ((uint32_t)f2bf(hp[1]) << 16);
        pw.y = (uint32_t)f2bf(hp[2]) | ((uint32_t)f2bf(hp[3]) << 16);
        pw.z = (uint32_t)f2bf(hp[4]) | ((uint32_t)f2bf(hp[5]) << 16);
        pw.w = (uint32_t)f2bf(hp[6]) | ((uint32_t)f2bf(hp[7]) << 16);
        *(uint4*)&a_sh[(((4 + grole) * 4 + gwq) * 16 + grow) * 8] = pw;
    }
    {
        float4 xv = *(const float4*)&x[(size_t)(b0 + arow) * II + xc];
        int kcx = xc >> 5, gx = (xc >> 3) & 3, jx = xc & 7;
        ushort4 p;
        p.x = f2bf(xv.x); p.y = f2bf(xv.y); p.z = f2bf(xv.z); p.w = f2bf(xv.w);
        *(ushort4*)&a_sh[((kcx * 4 + gx) * 16 + arow) * 8 + jx] = p;
    }

    for (int t = 0; t <= TT; ++t) {
        // prefetch x_{t+1} (issued before the poll; consumed after barrier B)
        float4 xn = make_float4(0.f, 0.f, 0.f, 0.f);
        if (t + 1 < TT)
            xn = *(const float4*)&x[(size_t)(t + 1) * (BB * II) + (size_t)(b0 + arow) * II + xc];

        if (t > 0 && grole != role) {   // own role filled by activation(t-1)
            const int par = (t - 1) & 1;
            const size_t gidx = ((((size_t)par * 32 + grp) * 8 + grole) * 16 + grow) * 16
                              + gwq * 4;
            const ull* pF = hbF + gidx;
            const ull* pS = hbS + gidx;
            u32x4 a0, a1;
            uint32_t it = 0;
            const uint32_t tt = (uint32_t)t;
            for (;;) {
                if (DUAL) {
                    u32x4 f0, f1;
                    asm volatile(
                        "global_load_dwordx4 %0, %2, off sc0\n\t"
                        "global_load_dwordx4 %1, %2, off offset:16 sc0\n\t"
                        "s_waitcnt vmcnt(0)"
                        : "=&v"(f0), "=&v"(f1) : "v"(pF) : "memory");
                    if (min(min(f0.y, f0.w), min(f1.y, f1.w)) >= tt) { a0 = f0; a1 = f1; break; }
                    ++it;
                    if ((it & 7) != 0) { __builtin_amdgcn_s_sleep(1); continue; }
                }
                u32x4 s0, s1;
                asm volatile(
                    "global_load_dwordx4 %0, %2, off sc0 sc1\n\t"
                    "global_load_dwordx4 %1, %2, off offset:16 sc0 sc1\n\t"
                    "s_waitcnt vmcnt(0)"
                    : "=&v"(s0), "=&v"(s1) : "v"(pS) : "memory");
                if (min(min(s0.y, s0.w), min(s1.y, s1.w)) >= tt) { a0 = s0; a1 = s1; break; }
                __builtin_amdgcn_s_sleep(1);
                if (!DUAL) ++it;
                if (it > (1u << 20)) { a0 = s0; a1 = s1; break; }  // hang-safety
            }
            uint32_t w0 = a0.x, w1 = a0.z, w2 = a1.x, w3 = a1.z;
            uint4 pw; pw.x = w0; pw.y = w1; pw.z = w2; pw.w = w3;
            *(uint4*)&a_sh[(((4 + grole) * 4 + gwq) * 16 + grow) * 8] = pw;
            float p = bf2lo(w0) * wfc8[0] + bf2hi(w0) * wfc8[1]
                    + bf2lo(w1) * wfc8[2] + bf2hi(w1) * wfc8[3]
                    + bf2lo(w2) * wfc8[4] + bf2hi(w2) * wfc8[5]
                    + bf2lo(w3) * wfc8[6] + bf2hi(w3) * wfc8[7];
            p += __shfl_xor(p, 1, 64);
            p += __shfl_xor(p, 2, 64);
            if (gwq == 0) zp_sh[t & 1][grole][grow] = p;
        }
        __syncthreads();  // A: a_sh (x_t, h_{t-1}) + zp_sh ready

        if (t == TT) {    // epilogue: emit z_{TT-1} only
            if (role == 0 && tid < 16) {
                float s = bfcs;
                #pragma unroll
                for (int r = 0; r < 8; ++r) s += zp_sh[TT & 1][r][tid];
                out[(size_t)(TT - 1) * BB + b0 + tid] = ftanh(s);
            }
            break;
        }

        // ---- MFMA: gates[16][128] = A[16][384] * Wregs, wave = n-tile ----
        f32x4 acc0 = {0.f, 0.f, 0.f, 0.f}, acc1 = {0.f, 0.f, 0.f, 0.f};
        #pragma unroll
        for (int kc = 0; kc < NKC; kc += 2) {
            bf16x8 a0 = *(const bf16x8*)&a_sh[((kc * 4 + (lane >> 4)) * 16 + (lane & 15)) * 8];
            acc0 = __builtin_amdgcn_mfma_f32_16x16x32_bf16(a0, wreg[kc], acc0, 0, 0, 0);
            bf16x8 a1 = *(const bf16x8*)&a_sh[(((kc + 1) * 4 + (lane >> 4)) * 16 + (lane & 15)) * 8];
            acc1 = __builtin_amdgcn_mfma_f32_16x16x32_bf16(a1, wreg[kc + 1], acc1, 0, 0, 0);
        }
        f32x4 acc = acc0 + acc1;
        {
            int r0 = (lane >> 4) * 4, cb = wv * 16 + (lane & 15);
            #pragma unroll
            for (int i = 0; i < 4; ++i) g_sh[(r0 + i) * GSTR + cb] = acc[i];
        }
        __syncthreads();  // B: gates ready; all a_sh reads done

        // stage x_{t+1}
        {
            int kcx = xc >> 5, gx = (xc >> 3) & 3, jx = xc & 7;
            ushort4 p;
            p.x = f2bf(xn.x); p.y = f2bf(xn.y); p.z = f2bf(xn.z); p.w = f2bf(xn.w);
            *(ushort4*)&a_sh[((kcx * 4 + gx) * 16 + arow) * 8 + jx] = p;
        }

        // ---- activation: one cell per thread ----
        float zp_;
        if (t == 0) {
            zp_ = z0r;
        } else {
            float s = bfcs;
            #pragma unroll
            for (int r = 0; r < 8; ++r) s += zp_sh[t & 1][r][arow];
            zp_ = ftanh(s);
            if (role == 0 && auu == 0)
                out[(size_t)(t - 1) * BB + b0 + arow] = zp_;
        }
        float gi = g_sh[arow * GSTR +      auu] + bia[0] + wzv[0] * zp_;
        float gf = g_sh[arow * GSTR + 32 + auu] + bia[1] + wzv[1] * zp_;
        float gg = g_sh[arow * GSTR + 64 + auu] + bia[2] + wzv[2] * zp_;
        float go = g_sh[arow * GSTR + 96 + auu] + bia[3] + wzv[3] * zp_;
        float ig = fsig(gi), fg = fsig(gf), gc = ftanh(gg), og = fsig(go);
        float cn = fg * c_r + ig * gc;
        c_r = cn;
        float hn = og * ftanh(cn);

        // own-role short-circuit: h pair -> a_sh directly; publish for peers
        uint32_t hb16 = f2bf(hn);
        uint32_t nb = __shfl_down(hb16, 1, 64);
        if (!(auu & 1)) {
            uint32_t word = hb16 | (nb << 16);
            *(uint32_t*)&a_sh[(((4 + role) * 4 + (auu >> 3)) * 16 + arow) * 8 + (auu & 7)]
                = word;
            ull q = ((ull)(uint32_t)(t + 1) << 32) | (ull)word;
            size_t o = ((((size_t)(t & 1) * 32 + grp) * 8 + role) * 16 + arow) * 16
                     + (auu >> 1);
            if (DUAL)
                asm volatile("global_store_dwordx2 %0, %1, off sc0"
                             :: "v"(hbF + o), "v"(q) : "memory");
            asm volatile("global_store_dwordx2 %0, %1, off sc0 sc1"
                         :: "v"(hbS + o), "v"(q) : "memory");
        }
        // own-role z partial for step t+1 (consumed after barrier A(t+1))
        float pz = hn * wfc;
        #pragma unroll
        for (int off = 16; off >= 1; off >>= 1) pz += __shfl_xor(pz, off, 32);
        if (auu == 0) zp_sh[(t + 1) & 1][role][arow] = pz;

        if (t == TT - 1) {
            size_t ho = (size_t)TT * BB + (size_t)(b0 + arow) * HH + u_g;
            out[ho] = hn;
            out[ho + (size_t)BB * HH] = cn;
        }
        // no barrier C: stamps make publishes self-synchronizing
    }
}

extern "C" void kernel_launch(void* const* d_in, const int* in_sizes, int n_in,
                              void* d_out, int out_size, void* d_ws, size_t ws_size,
                              hipStream_t stream) {
    const float* x    = (const float*)d_in[0];
    const float* h0   = (const float*)d_in[1];
    const float* c0   = (const float*)d_in[2];
    const float* z0   = (const float*)d_in[3];
    const float* W_ih = (const float*)d_in[4];
    const float* W_hh = (const float*)d_in[5];
    const float* b_ih = (const float*)d_in[6];
    const float* b_hh = (const float*)d_in[7];
    const float* Wfc  = (const float*)d_in[8];
    const float* bfc  = (const float*)d_in[9];
    float* out = (float*)d_out;

    const size_t COPY = (size_t)2 * 32 * 8 * 16 * 16 * 8;  // 1 MB per copy
    if (ws_size >= 2 * COPY) {
        ull* hbF = (ull*)d_ws;
        ull* hbS = (ull*)((char*)d_ws + COPY);
        hipMemsetAsync(d_ws, 0, 2 * COPY, stream);  // zero stamps (replay-safe)
        lstm_kernel<1><<<256, 512, 0, stream>>>(x, h0, c0, z0, W_ih, W_hh,
                                                b_ih, b_hh, Wfc, bfc,
                                                hbF, hbS, out);
    } else {
        ull* hbS = (ull*)d_ws;
        hipMemsetAsync(d_ws, 0, COPY, stream);
        lstm_kernel<0><<<256, 512, 0, stream>>>(x, h0, c0, z0, W_ih, W_hh,
                                                b_ih, b_hh, Wfc, bfc,
                                                hbS, hbS, out);
    }
}